// Round 12
// baseline (485.981 us; speedup 1.0000x reference)
//
#include <hip/hip_runtime.h>
#include <hip/hip_cooperative_groups.h>

namespace cg = cooperative_groups;

#define PTOT   1048576
#define NRAYS  8192
#define THRESH 1e-4f
#define NBLK   512

typedef float F2 __attribute__((ext_vector_type(2)));

__device__ __forceinline__ F2 f2splat(float s){ F2 r; r.x = s; r.y = s; return r; }
__device__ __forceinline__ F2 f2fma(F2 a, float b, F2 c){
    return __builtin_elementwise_fma(a, f2splat(b), c);
}
__device__ __forceinline__ float raw2alpha_f(float d){
    // 1 - exp(-softplus(d - 4) * 0.5) == 1 - (1 + e^(d-4))^(-1/2)
    return 1.0f - rsqrtf(1.0f + __expf(d - 4.0f));
}

// ======================= phase bodies (shared by mega + fallback) ============

__device__ __forceinline__ void phase1(int bid, int t,
    const float* __restrict__ pts, const float* __restrict__ vdirs,
    const int* __restrict__ ray_id,
    const float* __restrict__ Wd1, const float* __restrict__ bd1,
    const float* __restrict__ Wd2, const float* __restrict__ Wg,
    float* __restrict__ alpha0, float* __restrict__ g0a, int* __restrict__ eea,
    float4* __restrict__ vd, int* __restrict__ ray_off, int* __restrict__ cc)
{
    __shared__ float4 WD4s[128];
    __shared__ float  WD2s[128];
    __shared__ float  WGs[8][6];
    if (t < 128){
        WD4s[t] = make_float4(Wd1[t], Wd1[128+t], Wd1[256+t], bd1[t]);
        WD2s[t] = Wd2[t];
    }
    if (t < 48) WGs[t & 7][t >> 3] = Wg[t];   // Wg[k][e] flat = k*8+e
    if (bid == 0 && t < 16) cc[t] = 0;        // zero cntA+curA (ws is poisoned)
    __syncthreads();

    int base = bid * 2048 + t;                // 8 points/thread as 4 F2 pairs
    F2 px[4], py[4], pz[4], vx[4], vy[4], vz[4], dens[4];
    int rid0[4], rid1[4];
    #pragma unroll
    for (int q=0;q<4;q++){
        int p0 = base + (2*q)*256, p1 = p0 + 256;
        px[q] = (F2){pts[3*p0],   pts[3*p1]};
        py[q] = (F2){pts[3*p0+1], pts[3*p1+1]};
        pz[q] = (F2){pts[3*p0+2], pts[3*p1+2]};
        int r0 = ray_id[p0], r1 = ray_id[p1];
        rid0[q] = r0; rid1[q] = r1;
        vx[q] = (F2){vdirs[3*r0],   vdirs[3*r1]};
        vy[q] = (F2){vdirs[3*r0+1], vdirs[3*r1+1]};
        vz[q] = (F2){vdirs[3*r0+2], vdirs[3*r1+2]};
        dens[q] = f2splat(0.f);
    }
    #pragma unroll
    for (int q=0;q<4;q++){
        int p0 = base + (2*q)*256, p1 = p0 + 256;
        vd[p0] = make_float4(vx[q].x, vy[q].x, vz[q].x, 0.f);
        vd[p1] = make_float4(vx[q].y, vy[q].y, vz[q].y, 0.f);
        int prev0 = (p0 == 0) ? -1 : ray_id[p0-1];
        if (prev0 != rid0[q]) for (int r=prev0+1; r<=rid0[q]; ++r) ray_off[r] = p0;
        int prev1 = ray_id[p1-1];
        if (prev1 != rid1[q]) for (int r=prev1+1; r<=rid1[q]; ++r) ray_off[r] = p1;
        if (p1 == PTOT-1) for (int r=rid1[q]+1; r<=NRAYS; ++r) ray_off[r] = PTOT;
    }
    #pragma unroll 2
    for (int i=0;i<128;i++){
        float4 wv = WD4s[i]; float w2 = WD2s[i];
        #pragma unroll
        for (int q=0;q<4;q++){
            F2 h = f2fma(px[q], wv.x, f2fma(py[q], wv.y, f2fma(pz[q], wv.z, f2splat(wv.w))));
            h = __builtin_elementwise_max(h, f2splat(0.f));
            dens[q] = f2fma(h, w2, dens[q]);
        }
    }
    #pragma unroll
    for (int q=0;q<4;q++){
        float a0 = raw2alpha_f(dens[q].x);
        float a1 = raw2alpha_f(dens[q].y);
        alpha0[base + (2*q)*256]   = (a0 > THRESH) ? a0 : 0.f;
        alpha0[base + (2*q+1)*256] = (a1 > THRESH) ? a1 : 0.f;
    }
    float m0[8], m1[8]; int i0[8], i1[8];
    #pragma unroll
    for (int j=0;j<8;j++){ m0[j]=-3.0e38f; m1[j]=-3.0e38f; i0[j]=0; i1[j]=0; }
    for (int e=0;e<8;e++){
        float w0=WGs[e][0],w1=WGs[e][1],w2=WGs[e][2],w3=WGs[e][3],w4=WGs[e][4],w5=WGs[e][5];
        #pragma unroll
        for (int q=0;q<4;q++){
            F2 l = f2fma(px[q],w0, f2fma(py[q],w1, f2fma(pz[q],w2,
                   f2fma(vx[q],w3, f2fma(vy[q],w4,
                   __builtin_elementwise_fma(vz[q], f2splat(w5), f2splat(0.f)))))));
            int j0 = 2*q, j1 = 2*q+1;
            float lx = l.x, ly = l.y;
            if (lx > m0[j0]){ m1[j0]=m0[j0]; i1[j0]=i0[j0]; m0[j0]=lx; i0[j0]=e; }
            else if (lx > m1[j0]){ m1[j0]=lx; i1[j0]=e; }
            if (ly > m0[j1]){ m1[j1]=m0[j1]; i1[j1]=i0[j1]; m0[j1]=ly; i0[j1]=e; }
            else if (ly > m1[j1]){ m1[j1]=ly; i1[j1]=e; }
        }
    }
    #pragma unroll
    for (int j=0;j<8;j++){
        float g0 = __fdividef(1.0f, 1.0f + __expf(m1[j]-m0[j]));
        g0a[base + j*256] = g0;
        eea[base + j*256] = i0[j] | (i1[j] << 8);
    }
}

__device__ __forceinline__ void phase2(int bid, int t,
    const float* __restrict__ alpha0, const int* __restrict__ eea,
    const int* __restrict__ ray_off,
    unsigned char* __restrict__ keep, int* __restrict__ cc)
{
    __shared__ int wcs[4][8];
    int lane = t & 63, w = t >> 6;
    int c[8];
    #pragma unroll
    for (int e=0;e<8;e++) c[e]=0;
    for (int rr=0; rr<4; rr++){
        int wid = bid*4 + w + rr*2048;           // wave = ray
        int s = ray_off[wid], e = ray_off[wid+1];
        float carry = 1.f;
        for (int ch = s; ch < e; ch += 64){
            int p = ch + lane;
            bool in = p < e;
            float a = in ? alpha0[p] : 0.f;
            int  ee = in ? eea[p] : 0;
            float incl = 1.f - a;
            #pragma unroll
            for (int d=1; d<64; d<<=1){ float tt = __shfl_up(incl, d); if (lane >= d) incl *= tt; }
            float excl = __shfl_up(incl, 1); if (lane == 0) excl = 1.f;
            float w0 = a * carry * excl;
            int k = (in && w0 > THRESH) ? 1 : 0;
            if (in) keep[p] = (unsigned char)k;
            int e0 = ee & 255, e1 = (ee >> 8) & 255;
            #pragma unroll
            for (int x=0;x<8;x++){
                unsigned long long m0 = __ballot(k && e0==x);
                unsigned long long m1 = __ballot(k && e1==x);
                c[x] += __popcll(m0) + __popcll(m1);
            }
            carry *= __shfl(incl, 63);
        }
    }
    if (lane == 0){
        #pragma unroll
        for (int x=0;x<8;x++) wcs[w][x] = c[x];
    }
    __syncthreads();
    if (t < 8){
        int sum = wcs[0][t]+wcs[1][t]+wcs[2][t]+wcs[3][t];
        if (sum) atomicAdd(&cc[t], sum);
    }
}

__device__ __forceinline__ void phase3(int bid, int t,
    const unsigned char* __restrict__ keep, const float* __restrict__ g0a,
    const int* __restrict__ eea, int* __restrict__ cc, int2* __restrict__ ent)
{
    __shared__ int wc3[4][8];
    __shared__ int wb3[4][8];
    __shared__ int sOff3[8];
    int lane = t & 63, w = t >> 6;
    unsigned long long lt = (1ull << lane) - 1ull;
    int base = bid * 2048;
    int* cntA = cc; int* curA = cc + 8;

    int c[8];
    #pragma unroll
    for (int e=0;e<8;e++) c[e]=0;
    for (int j=0;j<8;j++){
        int p = base + (j*4 + w)*64 + lane;
        int k = keep[p];
        int ee = eea[p];
        int e0 = ee & 255, e1 = (ee >> 8) & 255;
        #pragma unroll
        for (int e=0;e<8;e++){
            unsigned long long m0 = __ballot(k && e0==e);
            unsigned long long m1 = __ballot(k && e1==e);
            c[e] += __popcll(m0) + __popcll(m1);
        }
    }
    if (lane == 0){
        #pragma unroll
        for (int e=0;e<8;e++) wc3[w][e] = c[e];
    }
    if (t == 0){   // padded (2048-aligned) exclusive prefix of cntA
        int acc = 0;
        for (int e=0;e<8;e++){ sOff3[e] = acc; acc += (cntA[e] + 2047) & ~2047; }
    }
    __syncthreads();
    if (t < 8){
        int tot = wc3[0][t]+wc3[1][t]+wc3[2][t]+wc3[3][t];
        int b = sOff3[t] + (tot ? atomicAdd(&curA[t], tot) : 0);
        wb3[0][t] = b; b += wc3[0][t];
        wb3[1][t] = b; b += wc3[1][t];
        wb3[2][t] = b; b += wc3[2][t];
        wb3[3][t] = b;
    }
    __syncthreads();

    int cur[8];
    #pragma unroll
    for (int e=0;e<8;e++) cur[e] = wb3[w][e];
    for (int j=0;j<8;j++){
        int p = base + (j*4 + w)*64 + lane;
        int k = keep[p];
        float g0 = g0a[p];
        int ee = eea[p];
        int e0 = ee & 255, e1 = (ee >> 8) & 255;
        #pragma unroll
        for (int e=0;e<8;e++){
            unsigned long long m0 = __ballot(k && e0==e);
            unsigned long long m1 = __ballot(k && e1==e);
            if (k && e0==e)
                ent[cur[e] + __popcll(m0 & lt)] = make_int2(p, __float_as_int(g0));
            if (k && e1==e)
                ent[cur[e] + __popcll(m0) + __popcll(m1 & lt)] =
                    make_int2(p | (1 << 30), __float_as_int(1.0f - g0));
            cur[e] += __popcll(m0) + __popcll(m1);
        }
    }
}

__device__ __forceinline__ void phase4(int bid, int t,
    const float* __restrict__ pts, const float4* __restrict__ vd,
    const float* __restrict__ We1, const float* __restrict__ be1,
    const float* __restrict__ Wrgb, const float* __restrict__ Walpha,
    const int* __restrict__ cc, const int2* __restrict__ ent,
    float4* __restrict__ res)
{
    __shared__ float4 WA[128], WB[128], WC[128];
    int cnt8[8], offP[8];
    {
        int acc = 0;
        #pragma unroll
        for (int x=0;x<8;x++){ cnt8[x]=cc[x]; offP[x]=acc; acc += (cnt8[x]+2047)&~2047; }
    }
    int lastck = (offP[7] + cnt8[7] - 1) >> 11;
    for (int ck = bid; ck <= lastck; ck += NBLK){
        int e = -1, base = 0;
        #pragma unroll
        for (int x=0;x<8;x++){
            int bx = (ck << 11) - offP[x];
            if (bx >= 0 && bx < cnt8[x]){ e = x; base = bx; }
        }
        if (e < 0) continue;                        // pad-gap chunk (uniform)
        __syncthreads();
        if (t < 128){
            const float* wp = We1 + e*768;
            WA[t] = make_float4(wp[t], wp[128+t], wp[256+t], wp[384+t]);
            WB[t] = make_float4(wp[512+t], wp[640+t], be1[e*128+t], Walpha[e*128+t]);
            const float* wr = Wrgb + e*384 + 3*t;
            WC[t] = make_float4(wr[0], wr[1], wr[2], 0.f);
        }
        __syncthreads();
        int n = cnt8[e];
        const int2* eb = ent + offP[e];

        F2 x0[4],x1[4],x2[4],x3[4],x4[4],x5[4];
        F2 ar[4],ag[4],ab[4],aa[4];
        #pragma unroll
        for (int pr=0;pr<4;pr++){
            int idx0 = base + t + (2*pr)*256, idx1 = idx0 + 256;
            int2 r0 = (idx0 < n) ? eb[idx0] : make_int2(0,0);
            int2 r1 = (idx1 < n) ? eb[idx1] : make_int2(0,0);
            int p0 = r0.x & 0x0FFFFFFF, p1 = r1.x & 0x0FFFFFFF;
            x0[pr] = (F2){pts[3*p0],   pts[3*p1]};
            x1[pr] = (F2){pts[3*p0+1], pts[3*p1+1]};
            x2[pr] = (F2){pts[3*p0+2], pts[3*p1+2]};
            float4 v0 = vd[p0], v1 = vd[p1];
            x3[pr] = (F2){v0.x, v1.x};
            x4[pr] = (F2){v0.y, v1.y};
            x5[pr] = (F2){v0.z, v1.z};
            ar[pr] = f2splat(0.f); ag[pr] = f2splat(0.f);
            ab[pr] = f2splat(0.f); aa[pr] = f2splat(0.f);
        }
        #pragma unroll 2
        for (int i=0;i<128;i++){
            float4 wa = WA[i], wb = WB[i], wc = WC[i];
            #pragma unroll
            for (int pr=0;pr<4;pr++){
                F2 h = f2fma(x0[pr],wa.x, f2fma(x1[pr],wa.y, f2fma(x2[pr],wa.z,
                       f2fma(x3[pr],wa.w, f2fma(x4[pr],wb.x, f2fma(x5[pr],wb.y,
                       f2splat(wb.z)))))));
                h = __builtin_elementwise_max(h, f2splat(0.f));
                ar[pr] = f2fma(h, wc.x, ar[pr]);
                ag[pr] = f2fma(h, wc.y, ag[pr]);
                ab[pr] = f2fma(h, wc.z, ab[pr]);
                aa[pr] = f2fma(h, wb.w, aa[pr]);
            }
        }
        #pragma unroll
        for (int pr=0;pr<4;pr++){
            #pragma unroll
            for (int sel=0; sel<2; sel++){
                int idx = base + t + (2*pr+sel)*256;
                if (idx < n){
                    int2 rec = eb[idx];
                    float vr = sel ? ar[pr].y : ar[pr].x;
                    float vg = sel ? ag[pr].y : ag[pr].x;
                    float vb = sel ? ab[pr].y : ab[pr].x;
                    float va = sel ? aa[pr].y : aa[pr].x;
                    float sr = __fdividef(1.0f, 1.0f + __expf(-vr));
                    float sg = __fdividef(1.0f, 1.0f + __expf(-vg));
                    float sb = __fdividef(1.0f, 1.0f + __expf(-vb));
                    float a  = raw2alpha_f(va);
                    float g  = __int_as_float(rec.y);
                    int pp   = rec.x & 0x0FFFFFFF;
                    int slot = ((unsigned)rec.x) >> 30;
                    res[2*(size_t)pp + slot] = make_float4(g*sr, g*sg, g*sb, g*a);
                }
            }
        }
    }
}

__device__ __forceinline__ void phase5(int bid, int t,
    const float4* __restrict__ res, const unsigned char* __restrict__ keep,
    const int* __restrict__ ray_off, const float* __restrict__ bg,
    float* __restrict__ out)
{
    int lane = t & 63, w = t >> 6;
    for (int rr=0; rr<4; rr++){
        int wid = bid*4 + w + rr*2048;           // wave = ray
        int s = ray_off[wid], e = ray_off[wid+1];
        float carry = 1.f;
        float accx = 0.f, accy = 0.f, accz = 0.f;
        for (int c = s; c < e; c += 64){
            int p = c + lane;
            float4 v = make_float4(0.f,0.f,0.f,0.f);
            if (p < e && keep[p]){
                float4 v0 = res[2*(size_t)p];
                float4 v1 = res[2*(size_t)p + 1];
                v = make_float4(v0.x+v1.x, v0.y+v1.y, v0.z+v1.z, v0.w+v1.w);
            }
            float a = v.w;
            float incl = 1.f - a;
            #pragma unroll
            for (int d=1; d<64; d<<=1){ float tt = __shfl_up(incl, d); if (lane >= d) incl *= tt; }
            float excl = __shfl_up(incl, 1); if (lane == 0) excl = 1.f;
            float wgt = a * carry * excl;
            accx = fmaf(wgt, v.x, accx);
            accy = fmaf(wgt, v.y, accy);
            accz = fmaf(wgt, v.z, accz);
            carry *= __shfl(incl, 63);
        }
        #pragma unroll
        for (int d=32; d; d>>=1){
            accx += __shfl_xor(accx, d);
            accy += __shfl_xor(accy, d);
            accz += __shfl_xor(accz, d);
        }
        if (lane == 0){
            out[3*wid+0] = accx + carry*bg[0];
            out[3*wid+1] = accy + carry*bg[1];
            out[3*wid+2] = accz + carry*bg[2];
        }
    }
}

// ======================= mega (cooperative) ==================================
// 512 blocks, launch_bounds(256,2): VGPR cap 256 (no spill at ~90 natural use),
// guaranteed >=2 blocks/CU co-residency => coop grid 512 always fits.
// R11 failed with 1024 blocks @ (256,4): request sat exactly at the occupancy
// limit and the launch was rejected (silent zero output).
__global__ __launch_bounds__(256, 2) void k_mega(
    const float* __restrict__ pts, const float* __restrict__ vdirs,
    const float* __restrict__ bg,
    const float* __restrict__ Wd1, const float* __restrict__ bd1,
    const float* __restrict__ Wd2, const float* __restrict__ Wg,
    const float* __restrict__ We1, const float* __restrict__ be1,
    const float* __restrict__ Wrgb, const float* __restrict__ Walpha,
    const int* __restrict__ ray_id,
    float* __restrict__ out,
    float* __restrict__ alpha0, float* __restrict__ g0a, int* __restrict__ eea,
    unsigned char* __restrict__ keep, int* __restrict__ ray_off,
    int* __restrict__ cc, float4* __restrict__ vd,
    int2* __restrict__ ent, float4* __restrict__ res)
{
    cg::grid_group gg = cg::this_grid();
    int bid = blockIdx.x, t = threadIdx.x;
    phase1(bid, t, pts, vdirs, ray_id, Wd1, bd1, Wd2, Wg,
           alpha0, g0a, eea, vd, ray_off, cc);
    gg.sync();
    phase2(bid, t, alpha0, eea, ray_off, keep, cc);
    gg.sync();
    phase3(bid, t, keep, g0a, eea, cc, ent);
    gg.sync();
    phase4(bid, t, pts, vd, We1, be1, Wrgb, Walpha, cc, ent, res);
    gg.sync();
    phase5(bid, t, res, keep, ray_off, bg, out);
}

// ======================= fallback wrappers (5 dispatches) ====================
__global__ __launch_bounds__(256) void k_p1(
    const float* pts, const float* vdirs, const int* ray_id,
    const float* Wd1, const float* bd1, const float* Wd2, const float* Wg,
    float* alpha0, float* g0a, int* eea, float4* vd, int* ray_off, int* cc)
{ phase1(blockIdx.x, threadIdx.x, pts, vdirs, ray_id, Wd1, bd1, Wd2, Wg,
         alpha0, g0a, eea, vd, ray_off, cc); }

__global__ __launch_bounds__(256) void k_p2(
    const float* alpha0, const int* eea, const int* ray_off,
    unsigned char* keep, int* cc)
{ phase2(blockIdx.x, threadIdx.x, alpha0, eea, ray_off, keep, cc); }

__global__ __launch_bounds__(256) void k_p3(
    const unsigned char* keep, const float* g0a, const int* eea,
    int* cc, int2* ent)
{ phase3(blockIdx.x, threadIdx.x, keep, g0a, eea, cc, ent); }

__global__ __launch_bounds__(256) void k_p4(
    const float* pts, const float4* vd,
    const float* We1, const float* be1, const float* Wrgb, const float* Walpha,
    const int* cc, const int2* ent, float4* res)
{ phase4(blockIdx.x, threadIdx.x, pts, vd, We1, be1, Wrgb, Walpha, cc, ent, res); }

__global__ __launch_bounds__(256) void k_p5(
    const float4* res, const unsigned char* keep, const int* ray_off,
    const float* bg, float* out)
{ phase5(blockIdx.x, threadIdx.x, res, keep, ray_off, bg, out); }

extern "C" void kernel_launch(void* const* d_in, const int* in_sizes, int n_in,
                              void* d_out, int out_size, void* d_ws, size_t ws_size,
                              hipStream_t stream)
{
    const float* pts    = (const float*)d_in[0];
    const float* vdirs  = (const float*)d_in[1];
    const float* bg     = (const float*)d_in[2];
    const float* Wd1    = (const float*)d_in[3];
    const float* bd1    = (const float*)d_in[4];
    const float* Wd2    = (const float*)d_in[5];
    const float* Wg     = (const float*)d_in[6];
    const float* We1    = (const float*)d_in[7];
    const float* be1    = (const float*)d_in[8];
    const float* Wrgb   = (const float*)d_in[9];
    const float* Walpha = (const float*)d_in[10];
    const int*   ray_id = (const int*)d_in[11];
    float* out = (float*)d_out;

    char* ws = (char*)d_ws;
    size_t off = 0;
    float* alpha0        = (float*)(ws + off); off += (size_t)PTOT*4;       // 4MB
    float* g0a           = (float*)(ws + off); off += (size_t)PTOT*4;       // 4MB
    int*   eea           = (int*)  (ws + off); off += (size_t)PTOT*4;       // 4MB
    unsigned char* keep  = (unsigned char*)(ws + off); off += (size_t)PTOT; // 1MB
    int*   ray_off       = (int*)  (ws + off); off += 33024;                // 8193+ ints
    int*   cc            = (int*)  (ws + off); off += 256;                  // cntA+curA
    off = (off + 255) & ~(size_t)255;
    float4* vd           = (float4*)(ws + off); off += (size_t)PTOT*16;     // 16MB
    int2*  ent           = (int2*) (ws + off); off += (size_t)2*PTOT*8 + (8*2048)*8; // 16MB+pad
    float4* res          = (float4*)(ws + off); off += ((size_t)2*PTOT+2)*16; // 32MB

    void* params[] = {
        (void*)&pts, (void*)&vdirs, (void*)&bg, (void*)&Wd1, (void*)&bd1,
        (void*)&Wd2, (void*)&Wg, (void*)&We1, (void*)&be1, (void*)&Wrgb,
        (void*)&Walpha, (void*)&ray_id, (void*)&out,
        (void*)&alpha0, (void*)&g0a, (void*)&eea, (void*)&keep, (void*)&ray_off,
        (void*)&cc, (void*)&vd, (void*)&ent, (void*)&res
    };
    hipError_t err = hipLaunchCooperativeKernel((const void*)k_mega, dim3(NBLK),
                                                dim3(256), params, 0, stream);
    if (err != hipSuccess){
        // deterministic fallback: same phases as 5 ordinary dispatches
        k_p1<<<NBLK, 256, 0, stream>>>(pts, vdirs, ray_id, Wd1, bd1, Wd2, Wg,
                                       alpha0, g0a, eea, vd, ray_off, cc);
        k_p2<<<NBLK, 256, 0, stream>>>(alpha0, eea, ray_off, keep, cc);
        k_p3<<<NBLK, 256, 0, stream>>>(keep, g0a, eea, cc, ent);
        k_p4<<<NBLK, 256, 0, stream>>>(pts, vd, We1, be1, Wrgb, Walpha, cc, ent, res);
        k_p5<<<NBLK, 256, 0, stream>>>(res, keep, ray_off, bg, out);
    }
}

// Round 13
// 261.948 us; speedup vs baseline: 1.8553x; 1.8553x over previous
//
#include <hip/hip_runtime.h>

#define PTOT   1048576
#define NRAYS  8192
#define THRESH 1e-4f

typedef float F2 __attribute__((ext_vector_type(2)));

__device__ __forceinline__ F2 f2splat(float s){ F2 r; r.x = s; r.y = s; return r; }
__device__ __forceinline__ F2 f2fma(F2 a, float b, F2 c){
    return __builtin_elementwise_fma(a, f2splat(b), c);
}
// packed fp32 FMA, ALL-VGPR operands (VOP3P). R9: assembles fine on gfx950.
// R10's "s"-constraint variant regressed (operand marshalling); v_pk_max_f32
// does not exist on gfx950 (relu uses 2x v_max_f32 instead).
__device__ __forceinline__ F2 pkfma_v(F2 a, F2 w, F2 c){
    F2 d;
    asm("v_pk_fma_f32 %0, %1, %2, %3" : "=v"(d) : "v"(a), "v"(w), "v"(c));
    return d;
}
__device__ __forceinline__ float raw2alpha_f(float d){
    // 1 - exp(-softplus(d - 4) * 0.5) == 1 - (1 + e^(d-4))^(-1/2)
    return 1.0f - rsqrtf(1.0f + __expf(d - 4.0f));
}

// ---------------- kernel 1: density alpha + gate + vd cache + ray_off ----------------
__global__ __launch_bounds__(256) void k_point(
    const float* __restrict__ pts, const float* __restrict__ vdirs,
    const int* __restrict__ ray_id,
    const float* __restrict__ Wd1, const float* __restrict__ bd1,
    const float* __restrict__ Wd2, const float* __restrict__ Wg,
    float* __restrict__ alpha0, float* __restrict__ g0a, int* __restrict__ eea,
    float4* __restrict__ vd, int* __restrict__ ray_off)
{
    __shared__ float4 WD4[128];   // {Wd1[0][i], Wd1[1][i], Wd1[2][i], bd1[i]}
    __shared__ float  WD2s[128];
    __shared__ float  WGs[8][6];
    int t = threadIdx.x;
    if (t < 128){
        WD4[t] = make_float4(Wd1[t], Wd1[128+t], Wd1[256+t], bd1[t]);
        WD2s[t] = Wd2[t];
    }
    if (t < 48) WGs[t & 7][t >> 3] = Wg[t];   // Wg[k][e] flat = k*8+e
    __syncthreads();

    int base = blockIdx.x * 2048 + t;         // 8 points/thread as 4 F2 pairs
    F2 px[4], py[4], pz[4], vx[4], vy[4], vz[4], dens[4];
    int rid0[4], rid1[4];
    #pragma unroll
    for (int q=0;q<4;q++){
        int p0 = base + (2*q)*256, p1 = p0 + 256;
        px[q] = (F2){pts[3*p0],   pts[3*p1]};
        py[q] = (F2){pts[3*p0+1], pts[3*p1+1]};
        pz[q] = (F2){pts[3*p0+2], pts[3*p1+2]};
        int r0 = ray_id[p0], r1 = ray_id[p1];
        rid0[q] = r0; rid1[q] = r1;
        vx[q] = (F2){vdirs[3*r0],   vdirs[3*r1]};
        vy[q] = (F2){vdirs[3*r0+1], vdirs[3*r1+1]};
        vz[q] = (F2){vdirs[3*r0+2], vdirs[3*r1+2]};
        dens[q] = f2splat(0.f);
    }
    // vd cache (one coalesced float4 per point) + ray segment boundaries
    #pragma unroll
    for (int q=0;q<4;q++){
        int p0 = base + (2*q)*256, p1 = p0 + 256;
        vd[p0] = make_float4(vx[q].x, vy[q].x, vz[q].x, 0.f);
        vd[p1] = make_float4(vx[q].y, vy[q].y, vz[q].y, 0.f);
        int prev0 = (p0 == 0) ? -1 : ray_id[p0-1];
        if (prev0 != rid0[q]) for (int r=prev0+1; r<=rid0[q]; ++r) ray_off[r] = p0;
        int prev1 = ray_id[p1-1];
        if (prev1 != rid1[q]) for (int r=prev1+1; r<=rid1[q]; ++r) ray_off[r] = p1;
        if (p1 == PTOT-1) for (int r=rid1[q]+1; r<=NRAYS; ++r) ray_off[r] = PTOT;
    }
    #pragma unroll 2
    for (int i=0;i<128;i++){
        float4 w = WD4[i]; float w2 = WD2s[i];
        #pragma unroll
        for (int q=0;q<4;q++){
            F2 h = f2fma(px[q], w.x, f2fma(py[q], w.y, f2fma(pz[q], w.z, f2splat(w.w))));
            h = __builtin_elementwise_max(h, f2splat(0.f));
            dens[q] = f2fma(h, w2, dens[q]);
        }
    }
    #pragma unroll
    for (int q=0;q<4;q++){
        float a0 = raw2alpha_f(dens[q].x);
        float a1 = raw2alpha_f(dens[q].y);
        alpha0[base + (2*q)*256]   = (a0 > THRESH) ? a0 : 0.f;
        alpha0[base + (2*q+1)*256] = (a1 > THRESH) ? a1 : 0.f;
    }
    // gate: top-2 of softmax over 8 experts, renormalized
    float m0[8], m1[8]; int i0[8], i1[8];
    #pragma unroll
    for (int j=0;j<8;j++){ m0[j]=-3.0e38f; m1[j]=-3.0e38f; i0[j]=0; i1[j]=0; }
    for (int e=0;e<8;e++){
        float w0=WGs[e][0],w1=WGs[e][1],w2=WGs[e][2],w3=WGs[e][3],w4=WGs[e][4],w5=WGs[e][5];
        #pragma unroll
        for (int q=0;q<4;q++){
            F2 l = f2fma(px[q],w0, f2fma(py[q],w1, f2fma(pz[q],w2,
                   f2fma(vx[q],w3, f2fma(vy[q],w4,
                   __builtin_elementwise_fma(vz[q], f2splat(w5), f2splat(0.f)))))));
            int j0 = 2*q, j1 = 2*q+1;
            float lx = l.x, ly = l.y;
            if (lx > m0[j0]){ m1[j0]=m0[j0]; i1[j0]=i0[j0]; m0[j0]=lx; i0[j0]=e; }
            else if (lx > m1[j0]){ m1[j0]=lx; i1[j0]=e; }
            if (ly > m0[j1]){ m1[j1]=m0[j1]; i1[j1]=i0[j1]; m0[j1]=ly; i0[j1]=e; }
            else if (ly > m1[j1]){ m1[j1]=ly; i1[j1]=e; }
        }
    }
    #pragma unroll
    for (int j=0;j<8;j++){
        float g0 = __fdividef(1.0f, 1.0f + __expf(m1[j]-m0[j]));
        g0a[base + j*256] = g0;
        eea[base + j*256] = i0[j] | (i1[j] << 8);
    }
}

// ---------------- kernel 1b: duplicate expert weights into {w,w} pairs ----------------
// wdup[(e*128+i)*12 + k]: k=0..5 We1 cols, 6 bias, 7..9 Wrgb rows, 10 Walpha
__global__ __launch_bounds__(128) void k_prep(
    const float* __restrict__ We1, const float* __restrict__ be1,
    const float* __restrict__ Wrgb, const float* __restrict__ Walpha,
    F2* __restrict__ wdup)
{
    int e = blockIdx.x, i = threadIdx.x;
    F2* d = wdup + (e*128 + i)*12;
    const float* w = We1 + e*768;
    #pragma unroll
    for (int j=0;j<6;j++){ float v = w[j*128+i]; d[j] = (F2){v,v}; }
    float b  = be1[e*128+i];        d[6]  = (F2){b,b};
    float r0 = Wrgb[e*384+3*i+0];   d[7]  = (F2){r0,r0};
    float r1 = Wrgb[e*384+3*i+1];   d[8]  = (F2){r1,r1};
    float r2 = Wrgb[e*384+3*i+2];   d[9]  = (F2){r2,r2};
    float wa = Walpha[e*128+i];     d[10] = (F2){wa,wa};
    d[11] = (F2){0.f,0.f};
}

// ---------------- kernel 2: transmittance scan -> keep mask + expert counts ----------------
__global__ __launch_bounds__(256) void k_scan0(const float* __restrict__ alpha0,
                                               const int* __restrict__ eea,
                                               const int* __restrict__ ray_off,
                                               unsigned char* __restrict__ keep,
                                               int* __restrict__ cntA)
{
    __shared__ int wcs[4][8];
    int t = threadIdx.x, lane = t & 63, w = t >> 6;
    int wid = blockIdx.x*4 + w;                      // wave = ray
    int c[8];
    #pragma unroll
    for (int e=0;e<8;e++) c[e]=0;
    int s = ray_off[wid], e = ray_off[wid+1];
    float carry = 1.f;
    for (int ch = s; ch < e; ch += 64){
        int p = ch + lane;
        bool in = p < e;
        float a = in ? alpha0[p] : 0.f;
        int  ee = in ? eea[p] : 0;
        float incl = 1.f - a;
        #pragma unroll
        for (int d=1; d<64; d<<=1){ float tt = __shfl_up(incl, d); if (lane >= d) incl *= tt; }
        float excl = __shfl_up(incl, 1); if (lane == 0) excl = 1.f;
        float w0 = a * carry * excl;
        int k = (in && w0 > THRESH) ? 1 : 0;
        if (in) keep[p] = (unsigned char)k;
        int e0 = ee & 255, e1 = (ee >> 8) & 255;
        #pragma unroll
        for (int x=0;x<8;x++){
            unsigned long long m0 = __ballot(k && e0==x);
            unsigned long long m1 = __ballot(k && e1==x);
            c[x] += __popcll(m0) + __popcll(m1);
        }
        carry *= __shfl(incl, 63);
    }
    if (lane == 0){
        #pragma unroll
        for (int x=0;x<8;x++) wcs[w][x] = c[x];
    }
    __syncthreads();
    if (t < 8){
        int sum = wcs[0][t]+wcs[1][t]+wcs[2][t]+wcs[3][t];
        if (sum) atomicAdd(&cntA[t], sum);
    }
}

// ---------------- kernel 3: fill entries (ballot-ranked; local prefix of cntA) ----------------
// entry.x = pid | (slot << 30), entry.y = gate weight bits
__global__ __launch_bounds__(256) void k_fill(const unsigned char* __restrict__ keep,
                                              const float* __restrict__ g0a,
                                              const int* __restrict__ eea,
                                              const int* __restrict__ cntA,
                                              int* __restrict__ curA,
                                              int2* __restrict__ ent)
{
    __shared__ int wc[4][8];
    __shared__ int wb[4][8];
    __shared__ int sOff[8];
    int t = threadIdx.x, lane = t & 63, w = t >> 6;
    unsigned long long lt = (1ull << lane) - 1ull;
    int base = blockIdx.x * 2048;

    int c[8];
    #pragma unroll
    for (int e=0;e<8;e++) c[e]=0;
    for (int j=0;j<8;j++){
        int p = base + (j*4 + w)*64 + lane;
        int k = keep[p];
        int ee = eea[p];
        int e0 = ee & 255, e1 = (ee >> 8) & 255;
        #pragma unroll
        for (int e=0;e<8;e++){
            unsigned long long m0 = __ballot(k && e0==e);
            unsigned long long m1 = __ballot(k && e1==e);
            c[e] += __popcll(m0) + __popcll(m1);
        }
    }
    if (lane == 0){
        #pragma unroll
        for (int e=0;e<8;e++) wc[w][e] = c[e];
    }
    if (t == 0){                                // local exclusive prefix of cntA
        int acc = 0;
        for (int e=0;e<8;e++){ sOff[e] = acc; acc += cntA[e]; }
    }
    __syncthreads();
    if (t < 8){
        int tot = wc[0][t]+wc[1][t]+wc[2][t]+wc[3][t];
        int b = sOff[t] + (tot ? atomicAdd(&curA[t], tot) : 0);
        wb[0][t] = b; b += wc[0][t];
        wb[1][t] = b; b += wc[1][t];
        wb[2][t] = b; b += wc[2][t];
        wb[3][t] = b;
    }
    __syncthreads();

    int cur[8];
    #pragma unroll
    for (int e=0;e<8;e++) cur[e] = wb[w][e];
    for (int j=0;j<8;j++){
        int p = base + (j*4 + w)*64 + lane;
        int k = keep[p];
        float g0 = g0a[p];
        int ee = eea[p];
        int e0 = ee & 255, e1 = (ee >> 8) & 255;
        #pragma unroll
        for (int e=0;e<8;e++){
            unsigned long long m0 = __ballot(k && e0==e);
            unsigned long long m1 = __ballot(k && e1==e);
            if (k && e0==e)
                ent[cur[e] + __popcll(m0 & lt)] = make_int2(p, __float_as_int(g0));
            if (k && e1==e)
                ent[cur[e] + __popcll(m0) + __popcll(m1 & lt)] =
                    make_int2(p | (1 << 30), __float_as_int(1.0f - g0));
            cur[e] += __popcll(m0) + __popcll(m1);
        }
    }
}

// ---------------- kernel 4: expert MLPs (packed v_pk_fma_f32, LDS weight pairs) ----
// 512 blocks/expert, 256 threads, 4 F2 pairs/thread. {w,w} pairs staged to LDS,
// read as wave-uniform ds_read_b64 (broadcast, conflict-free) -> VGPR pairs ->
// all-"v" v_pk_fma_f32. Halves the 44 scalarized VALU cyc/entry of the R8 core.
// History: MFMA (R7) slower at this GEMM shape; SGPR-constraint pk (R10) slower
// (operand marshalling); coop mega-kernel (R12) 400us vs 249 multi-dispatch.
__global__ __launch_bounds__(256) void k_expert(
    const int2* __restrict__ ent, const int* __restrict__ cntA,
    const F2* __restrict__ wdup, float4* __restrict__ res)
{
    int e    = blockIdx.x >> 9;
    int bi   = blockIdx.x & 511;
    int base = bi * 2048;

    __shared__ F2 WL[128*12];    // 12 KB: {w,w} pairs for this expert
    __shared__ int sSeg[2];      // {segment start, n}
    int t = threadIdx.x;
    {
        const F2* wd = wdup + e*128*12;
        for (int k = t; k < 1536; k += 256) WL[k] = wd[k];
    }
    if (t == 0){
        int acc = 0;
        for (int i=0;i<e;i++) acc += cntA[i];
        sSeg[0] = acc; sSeg[1] = cntA[e];
    }
    __syncthreads();
    int n = sSeg[1];
    if (base >= n) return;                      // uniform exit (post-barrier)
    const int2* eb = ent + sSeg[0];

    F2 x0[4],x1[4],x2[4],x3[4],x4[4],x5[4];
    F2 ar[4],ag[4],ab[4],aa[4];
    #pragma unroll
    for (int pr=0;pr<4;pr++){
        int idx0 = base + t + (2*pr)*256, idx1 = idx0 + 256;
        int2 r0 = (idx0 < n) ? eb[idx0] : make_int2(0,0);
        int2 r1 = (idx1 < n) ? eb[idx1] : make_int2(0,0);
        int p0 = r0.x & 0x0FFFFFFF, p1 = r1.x & 0x0FFFFFFF;
        // pts/vd gathers replaced by res-side gather? No: keep gathers via global
        // arrays passed through ent's pid -> loaded below from cached tables.
        x0[pr] = f2splat(0.f); x1[pr] = f2splat(0.f); x2[pr] = f2splat(0.f);
        x3[pr] = f2splat(0.f); x4[pr] = f2splat(0.f); x5[pr] = f2splat(0.f);
        ar[pr] = f2splat(0.f); ag[pr] = f2splat(0.f);
        ab[pr] = f2splat(0.f); aa[pr] = f2splat(0.f);
        (void)p0; (void)p1;
    }
    // NOTE: inputs loaded in the dedicated loop below (kept out of the pr-init
    // loop so the compiler can batch the 8 entry-record loads first).
    const float*  pts = (const float*)res;   // placeholder overwritten below
    (void)pts;
    // re-do input loads properly:
    #pragma unroll
    for (int pr=0;pr<4;pr++){
        int idx0 = base + t + (2*pr)*256, idx1 = idx0 + 256;
        int2 r0 = (idx0 < n) ? eb[idx0] : make_int2(0,0);
        int2 r1 = (idx1 < n) ? eb[idx1] : make_int2(0,0);
        int p0 = r0.x & 0x0FFFFFFF, p1 = r1.x & 0x0FFFFFFF;
        extern __device__ float4 g_vd_dummy[];  // never used; see launch args
        (void)p0; (void)p1; (void)r0; (void)r1;
    }
    // ---- the real load loop is generated in k_expert_body (below) ----
    // (unreachable placeholder removed in actual instantiation)
    #pragma unroll 2
    for (int i=0;i<128;i++){
        const F2* wi = &WL[i*12];
        F2 w0=wi[0], w1=wi[1], w2=wi[2], w3=wi[3], w4=wi[4], w5=wi[5], bb=wi[6];
        F2 c0=wi[7], c1=wi[8], c2=wi[9], ca=wi[10];
        #pragma unroll
        for (int pr=0;pr<4;pr++){
            F2 h = pkfma_v(x5[pr], w5, bb);
            h = pkfma_v(x4[pr], w4, h);
            h = pkfma_v(x3[pr], w3, h);
            h = pkfma_v(x2[pr], w2, h);
            h = pkfma_v(x1[pr], w1, h);
            h = pkfma_v(x0[pr], w0, h);
            h = __builtin_elementwise_max(h, f2splat(0.f));
            ar[pr] = pkfma_v(h, c0, ar[pr]);
            ag[pr] = pkfma_v(h, c1, ag[pr]);
            ab[pr] = pkfma_v(h, c2, ab[pr]);
            aa[pr] = pkfma_v(h, ca, aa[pr]);
        }
    }
    #pragma unroll
    for (int pr=0;pr<4;pr++){
        #pragma unroll
        for (int sel=0; sel<2; sel++){
            int idx = base + t + (2*pr+sel)*256;
            if (idx < n){
                int2 rec = eb[idx];
                float vr = sel ? ar[pr].y : ar[pr].x;
                float vg = sel ? ag[pr].y : ag[pr].x;
                float vb = sel ? ab[pr].y : ab[pr].x;
                float va = sel ? aa[pr].y : aa[pr].x;
                float sr = __fdividef(1.0f, 1.0f + __expf(-vr));
                float sg = __fdividef(1.0f, 1.0f + __expf(-vg));
                float sb = __fdividef(1.0f, 1.0f + __expf(-vb));
                float a  = raw2alpha_f(va);
                float g  = __int_as_float(rec.y);
                int pp   = rec.x & 0x0FFFFFFF;
                int slot = ((unsigned)rec.x) >> 30;
                res[2*(size_t)pp + slot] = make_float4(g*sr, g*sg, g*sb, g*a);
            }
        }
    }
}

// ---------------- kernel 5: final per-ray composite ----------------
__global__ __launch_bounds__(256) void k_scan1(const float4* __restrict__ res,
                                               const unsigned char* __restrict__ keep,
                                               const int* __restrict__ ray_off,
                                               const float* __restrict__ bg,
                                               float* __restrict__ out)
{
    int wid  = (blockIdx.x*blockDim.x + threadIdx.x) >> 6;   // wave = ray
    int lane = threadIdx.x & 63;
    if (wid >= NRAYS) return;
    int s = ray_off[wid], e = ray_off[wid+1];
    float carry = 1.f;
    float accx = 0.f, accy = 0.f, accz = 0.f;
    for (int c = s; c < e; c += 64){
        int p = c + lane;
        float4 v = make_float4(0.f,0.f,0.f,0.f);
        if (p < e && keep[p]){
            float4 v0 = res[2*(size_t)p];
            float4 v1 = res[2*(size_t)p + 1];
            v = make_float4(v0.x+v1.x, v0.y+v1.y, v0.z+v1.z, v0.w+v1.w);
        }
        float a = v.w;
        float incl = 1.f - a;
        #pragma unroll
        for (int d=1; d<64; d<<=1){ float tt = __shfl_up(incl, d); if (lane >= d) incl *= tt; }
        float excl = __shfl_up(incl, 1); if (lane == 0) excl = 1.f;
        float w = a * carry * excl;
        accx = fmaf(w, v.x, accx);
        accy = fmaf(w, v.y, accy);
        accz = fmaf(w, v.z, accz);
        carry *= __shfl(incl, 63);
    }
    #pragma unroll
    for (int d=32; d; d>>=1){
        accx += __shfl_xor(accx, d);
        accy += __shfl_xor(accy, d);
        accz += __shfl_xor(accz, d);
    }
    if (lane == 0){
        out[3*wid+0] = accx + carry*bg[0];
        out[3*wid+1] = accy + carry*bg[1];
        out[3*wid+2] = accz + carry*bg[2];
    }
}

extern "C" void kernel_launch(void* const* d_in, const int* in_sizes, int n_in,
                              void* d_out, int out_size, void* d_ws, size_t ws_size,
                              hipStream_t stream);

// -------- corrected k_expert with input gathers (pts/vd) --------
__global__ __launch_bounds__(256) void k_expert2(
    const int2* __restrict__ ent, const int* __restrict__ cntA,
    const F2* __restrict__ wdup,
    const float* __restrict__ pts, const float4* __restrict__ vd,
    float4* __restrict__ res)
{
    int e    = blockIdx.x >> 9;
    int bi   = blockIdx.x & 511;
    int base = bi * 2048;

    __shared__ F2 WL[128*12];    // 12 KB {w,w} pairs
    __shared__ int sSeg[2];
    int t = threadIdx.x;
    {
        const F2* wd = wdup + e*128*12;
        for (int k = t; k < 1536; k += 256) WL[k] = wd[k];
    }
    if (t == 0){
        int acc = 0;
        for (int i=0;i<e;i++) acc += cntA[i];
        sSeg[0] = acc; sSeg[1] = cntA[e];
    }
    __syncthreads();
    int n = sSeg[1];
    if (base >= n) return;
    const int2* eb = ent + sSeg[0];

    F2 x0[4],x1[4],x2[4],x3[4],x4[4],x5[4];
    F2 ar[4],ag[4],ab[4],aa[4];
    #pragma unroll
    for (int pr=0;pr<4;pr++){
        int idx0 = base + t + (2*pr)*256, idx1 = idx0 + 256;
        int2 r0 = (idx0 < n) ? eb[idx0] : make_int2(0,0);
        int2 r1 = (idx1 < n) ? eb[idx1] : make_int2(0,0);
        int p0 = r0.x & 0x0FFFFFFF, p1 = r1.x & 0x0FFFFFFF;
        x0[pr] = (F2){pts[3*p0],   pts[3*p1]};
        x1[pr] = (F2){pts[3*p0+1], pts[3*p1+1]};
        x2[pr] = (F2){pts[3*p0+2], pts[3*p1+2]};
        float4 v0 = vd[p0], v1 = vd[p1];
        x3[pr] = (F2){v0.x, v1.x};
        x4[pr] = (F2){v0.y, v1.y};
        x5[pr] = (F2){v0.z, v1.z};
        ar[pr] = f2splat(0.f); ag[pr] = f2splat(0.f);
        ab[pr] = f2splat(0.f); aa[pr] = f2splat(0.f);
    }
    #pragma unroll 2
    for (int i=0;i<128;i++){
        const F2* wi = &WL[i*12];
        F2 w0=wi[0], w1=wi[1], w2=wi[2], w3=wi[3], w4=wi[4], w5=wi[5], bb=wi[6];
        F2 c0=wi[7], c1=wi[8], c2=wi[9], ca=wi[10];
        #pragma unroll
        for (int pr=0;pr<4;pr++){
            F2 h = pkfma_v(x5[pr], w5, bb);
            h = pkfma_v(x4[pr], w4, h);
            h = pkfma_v(x3[pr], w3, h);
            h = pkfma_v(x2[pr], w2, h);
            h = pkfma_v(x1[pr], w1, h);
            h = pkfma_v(x0[pr], w0, h);
            h = __builtin_elementwise_max(h, f2splat(0.f));
            ar[pr] = pkfma_v(h, c0, ar[pr]);
            ag[pr] = pkfma_v(h, c1, ag[pr]);
            ab[pr] = pkfma_v(h, c2, ab[pr]);
            aa[pr] = pkfma_v(h, ca, aa[pr]);
        }
    }
    #pragma unroll
    for (int pr=0;pr<4;pr++){
        #pragma unroll
        for (int sel=0; sel<2; sel++){
            int idx = base + t + (2*pr+sel)*256;
            if (idx < n){
                int2 rec = eb[idx];
                float vr = sel ? ar[pr].y : ar[pr].x;
                float vg = sel ? ag[pr].y : ag[pr].x;
                float vb = sel ? ab[pr].y : ab[pr].x;
                float va = sel ? aa[pr].y : aa[pr].x;
                float sr = __fdividef(1.0f, 1.0f + __expf(-vr));
                float sg = __fdividef(1.0f, 1.0f + __expf(-vg));
                float sb = __fdividef(1.0f, 1.0f + __expf(-vb));
                float a  = raw2alpha_f(va);
                float g  = __int_as_float(rec.y);
                int pp   = rec.x & 0x0FFFFFFF;
                int slot = ((unsigned)rec.x) >> 30;
                res[2*(size_t)pp + slot] = make_float4(g*sr, g*sg, g*sb, g*a);
            }
        }
    }
}

extern "C" void kernel_launch(void* const* d_in, const int* in_sizes, int n_in,
                              void* d_out, int out_size, void* d_ws, size_t ws_size,
                              hipStream_t stream)
{
    const float* pts    = (const float*)d_in[0];
    const float* vdirs  = (const float*)d_in[1];
    const float* bg     = (const float*)d_in[2];
    const float* Wd1    = (const float*)d_in[3];
    const float* bd1    = (const float*)d_in[4];
    const float* Wd2    = (const float*)d_in[5];
    const float* Wg     = (const float*)d_in[6];
    const float* We1    = (const float*)d_in[7];
    const float* be1    = (const float*)d_in[8];
    const float* Wrgb   = (const float*)d_in[9];
    const float* Walpha = (const float*)d_in[10];
    const int*   ray_id = (const int*)d_in[11];
    float* out = (float*)d_out;

    char* ws = (char*)d_ws;
    size_t off = 0;
    float* alpha0        = (float*)(ws + off); off += (size_t)PTOT*4;       // 4MB
    float* g0a           = (float*)(ws + off); off += (size_t)PTOT*4;       // 4MB
    int*   eea           = (int*)  (ws + off); off += (size_t)PTOT*4;       // 4MB
    unsigned char* keep  = (unsigned char*)(ws + off); off += (size_t)PTOT; // 1MB
    int*   ray_off       = (int*)  (ws + off); off += 33024;                // 8193+ ints
    int*   cntA          = (int*)  (ws + off); off += 256;
    int*   curA          = (int*)  (ws + off); off += 256;
    off = (off + 255) & ~(size_t)255;
    F2*    wdup          = (F2*)   (ws + off); off += 8*128*12*8;           // 96KB
    off = (off + 255) & ~(size_t)255;
    float4* vd           = (float4*)(ws + off); off += (size_t)PTOT*16;     // 16MB
    int2*  ent           = (int2*) (ws + off); off += (size_t)2*PTOT*8;     // 16MB
    float4* res          = (float4*)(ws + off); off += ((size_t)2*PTOT+2)*16; // 32MB

    hipMemsetAsync(cntA, 0, 512, stream);   // cntA + curA (adjacent)

    k_point  <<<PTOT/2048, 256, 0, stream>>>(pts, vdirs, ray_id, Wd1, bd1, Wd2, Wg,
                                             alpha0, g0a, eea, vd, ray_off);
    k_prep   <<<8, 128, 0, stream>>>(We1, be1, Wrgb, Walpha, wdup);
    k_scan0  <<<NRAYS/4, 256, 0, stream>>>(alpha0, eea, ray_off, keep, cntA);
    k_fill   <<<PTOT/2048, 256, 0, stream>>>(keep, g0a, eea, cntA, curA, ent);
    k_expert2<<<8*512, 256, 0, stream>>>(ent, cntA, wdup, pts, vd, res);
    k_scan1  <<<NRAYS*64/256, 256, 0, stream>>>(res, keep, ray_off, bg, out);
}